// Round 8
// baseline (92.607 us; speedup 1.0000x reference)
//
#include <hip/hip_runtime.h>
#include <math.h>

namespace {
constexpr int kB = 16;
constexpr int kL = 240000;
constexpr int kD = 9;
constexpr float kInvSamp = 1.0f / 24000.0f;
constexpr int kChunk = 2048;
constexpr int kT = 8;              // samples per thread
constexpr int kThreads = 256;      // kChunk / kT
constexpr int kNChunks = 118;      // ceil(240000/2048); last chunk 384 samp
constexpr float kSineAmp = 0.1f;
constexpr float kNoiseStd = 0.003f;
constexpr float kNoiseUnv = (float)(0.1 / 3.0);
typedef float vfloat4 __attribute__((ext_vector_type(4)));
}  // namespace

// ---------------- Pass A: per-chunk sum of rq = f0/SR -> agg[b*118+c]
__global__ __launch_bounds__(kThreads) void sine_pass_a(
    const float* __restrict__ f0, double* __restrict__ agg) {
  const int c = blockIdx.x, b = blockIdx.y, tid = threadIdx.x;
  const int l0 = c * kChunk + tid * kT;
  float s = 0.0f;
  if (l0 < kL) {
    const float4* f4 = reinterpret_cast<const float4*>(f0 + (size_t)b * kL + l0);
    const float4 a = f4[0], bb = f4[1];
    s = ((a.x + a.y) + (a.z + a.w)) + ((bb.x + bb.y) + (bb.z + bb.w));
  }
  double v = (double)s * (double)kInvSamp;
  // wave reduce (butterfly), then 4 partials via LDS
#pragma unroll
  for (int ofs = 1; ofs < 64; ofs <<= 1) v += __shfl_xor(v, ofs, 64);
  __shared__ double wt[4];
  const int wid = tid >> 6;
  if ((tid & 63) == 0) wt[wid] = v;
  __syncthreads();
  if (tid == 0) agg[(size_t)b * kNChunks + c] = wt[0] + wt[1] + wt[2] + wt[3];
}

// ---------------- Pass C: predecessor reduce + block scan + emit
__global__ __launch_bounds__(kThreads) void sine_emit(
    const float* __restrict__ f0, const float* __restrict__ rand_ini,
    const float* __restrict__ noise, const float* __restrict__ w,
    const double* __restrict__ agg, float* __restrict__ out) {
  const int c = blockIdx.x, b = blockIdx.y, tid = threadIdx.x;
  const int lane = tid & 63, wid = tid >> 6;
  const int l0 = c * kChunk + tid * kT;
  const bool active = l0 < kL;

  // ---- issue order matters (vmcnt is FIFO): f0, agg, then noise ----
  float rq[kT];
  float tsum = 0.0f;
  if (active) {
    const float4* f4 = reinterpret_cast<const float4*>(f0 + (size_t)b * kL + l0);
    const float4 a = f4[0], bb = f4[1];
    rq[0] = a.x * kInvSamp; rq[1] = a.y * kInvSamp;
    rq[2] = a.z * kInvSamp; rq[3] = a.w * kInvSamp;
    rq[4] = bb.x * kInvSamp; rq[5] = bb.y * kInvSamp;
    rq[6] = bb.z * kInvSamp; rq[7] = bb.w * kInvSamp;
#pragma unroll
    for (int j = 0; j < kT; ++j) tsum += rq[j];
  } else {
#pragma unroll
    for (int j = 0; j < kT; ++j) rq[j] = 0.0f;
  }

  // predecessor aggregate for this lane (L2-resident after pass A)
  double pv = (tid < c) ? agg[(size_t)b * kNChunks + tid] : 0.0;

  // streaming noise loads (no reuse): issue all 18 early, nontemporal
  vfloat4 nzv[18];
  if (active) {
    const vfloat4* n4 =
        reinterpret_cast<const vfloat4*>(noise + ((size_t)b * kL + l0) * kD);
#pragma unroll
    for (int i = 0; i < 18; ++i) nzv[i] = __builtin_nontemporal_load(n4 + i);
  }

  // ---- wave-level reduce (pred aggs) + wave-level scan (tsum), 1 barrier
#pragma unroll
  for (int ofs = 1; ofs < 64; ofs <<= 1) pv += __shfl_xor(pv, ofs, 64);

  double incl = (double)tsum;  // wave-inclusive scan
#pragma unroll
  for (int ofs = 1; ofs < 64; ofs <<= 1) {
    const double u = __shfl_up(incl, ofs, 64);
    if (lane >= ofs) incl += u;
  }

  __shared__ double rtot[4], wtot[4];
  if (lane == 0) rtot[wid] = pv;
  if (lane == 63) wtot[wid] = incl;
  __syncthreads();

  if (!active) return;

  double base = rtot[0] + rtot[1] + rtot[2] + rtot[3];  // pred-chunk sum
#pragma unroll
  for (int k = 0; k < 4; ++k)
    if (k < wid) base += wtot[k];  // preceding-wave totals
  const double cbase = base + incl - (double)tsum;  // exclusive prefix

  float basef[kD], wv[kD];
#pragma unroll
  for (int d = 0; d < kD; ++d) {
    const double ph = (double)(d + 1) * cbase + (double)rand_ini[b * kD + d];
    basef[d] = (float)(ph - floor(ph));
    wv[d] = w[d];
  }

  // ---- all sine dots first (pure VALU; noise loads still in flight)
  float dots[kT];
  float pref = 0.0f;
#pragma unroll
  for (int j = 0; j < kT; ++j) {
    pref += rq[j];  // inclusive local prefix
    float s = 0.0f;
#pragma unroll
    for (int d = 0; d < kD; ++d) {
      const float pf = __builtin_amdgcn_fractf(basef[d] + (float)(d + 1) * pref);
      s = fmaf(wv[d], __builtin_amdgcn_sinf(pf), s);  // sin(2*pi*frac)
    }
    dots[j] = s;
  }

  // ---- noise dots + tanh + store (consumes loads in issue order)
  const float* nz = reinterpret_cast<const float*>(nzv);
  float ob[kT];
#pragma unroll
  for (int j = 0; j < kT; ++j) {
    const float f = rq[j];
    const float au = (f > 0.0f) ? kSineAmp : 0.0f;
    const float namp = (f > 0.0f) ? kNoiseStd : kNoiseUnv;
    float dotn = 0.0f;
#pragma unroll
    for (int d = 0; d < kD; ++d) dotn = fmaf(wv[d], nz[j * kD + d], dotn);
    const float x = au * dots[j] + namp * dotn;
    const float e = __expf(2.0f * x);
    ob[j] = 1.0f - 2.0f * __builtin_amdgcn_rcpf(e + 1.0f);  // tanh(x)
  }

  float4* o4 = reinterpret_cast<float4*>(out + (size_t)b * kL + l0);
  o4[0] = make_float4(ob[0], ob[1], ob[2], ob[3]);
  o4[1] = make_float4(ob[4], ob[5], ob[6], ob[7]);
}

extern "C" void kernel_launch(void* const* d_in, const int* in_sizes, int n_in,
                              void* d_out, int out_size, void* d_ws,
                              size_t ws_size, hipStream_t stream) {
  const float* f0 = (const float*)d_in[0];
  const float* rand_ini = (const float*)d_in[1];
  const float* noise = (const float*)d_in[2];
  const float* w = (const float*)d_in[3];
  float* out = (float*)d_out;
  double* agg = (double*)d_ws;  // kB * kNChunks doubles = 15104 B

  const dim3 grid(kNChunks, kB), block(kThreads);
  sine_pass_a<<<grid, block, 0, stream>>>(f0, agg);
  sine_emit<<<grid, block, 0, stream>>>(f0, rand_ini, noise, w, agg, out);
}

// Round 9
// 35.657 us; speedup vs baseline: 2.5972x; 2.5972x over previous
//
#include <hip/hip_runtime.h>
#include <math.h>

namespace {
constexpr int kB = 16;
constexpr int kL = 240000;
constexpr int kD = 9;
constexpr float kInvSamp = 1.0f / 24000.0f;
constexpr int kChunk = 2048;
constexpr int kT = 8;              // samples per thread
constexpr int kThreads = 256;      // kChunk / kT
constexpr int kNChunks = 118;      // ceil(240000/2048); last chunk 384 samp
constexpr float kSineAmp = 0.1f;
constexpr float kNoiseStd = 0.003f;
constexpr float kNoiseUnv = (float)(0.1 / 3.0);
}  // namespace

// ---------------- Pass A: per-chunk sum of rq = f0/SR -> agg[b*118+c]
__global__ __launch_bounds__(kThreads) void sine_pass_a(
    const float* __restrict__ f0, double* __restrict__ agg) {
  const int c = blockIdx.x, b = blockIdx.y, tid = threadIdx.x;
  const int l0 = c * kChunk + tid * kT;
  float s = 0.0f;
  if (l0 < kL) {
    const float4* f4 = reinterpret_cast<const float4*>(f0 + (size_t)b * kL + l0);
    const float4 a = f4[0], bb = f4[1];
    s = ((a.x + a.y) + (a.z + a.w)) + ((bb.x + bb.y) + (bb.z + bb.w));
  }
  double v = (double)s * (double)kInvSamp;
  // wave reduce (butterfly), then 4 partials via LDS
#pragma unroll
  for (int ofs = 1; ofs < 64; ofs <<= 1) v += __shfl_xor(v, ofs, 64);
  __shared__ double wt[4];
  const int wid = tid >> 6;
  if ((tid & 63) == 0) wt[wid] = v;
  __syncthreads();
  if (tid == 0) agg[(size_t)b * kNChunks + c] = wt[0] + wt[1] + wt[2] + wt[3];
}

// ---------------- Pass C: predecessor reduce + block scan + emit
__global__ __launch_bounds__(kThreads) void sine_emit(
    const float* __restrict__ f0, const float* __restrict__ rand_ini,
    const float* __restrict__ noise, const float* __restrict__ w,
    const double* __restrict__ agg, float* __restrict__ out) {
  __shared__ double sc[kThreads];
  __shared__ double red[kThreads];
  const int c = blockIdx.x, b = blockIdx.y, tid = threadIdx.x;
  const int l0 = c * kChunk + tid * kT;
  const bool active = l0 < kL;

  // ---- issue order matters (vmcnt is FIFO): f0 (2), agg (1), noise (18).
  // Waiting on agg then costs vmcnt(18) -- reduce+scan overlap the noise
  // loads still in flight (R6 had agg last => vmcnt(0) drained everything).
  float rq[kT];
  float tsum = 0.0f;
  if (active) {
    const float4* f4 = reinterpret_cast<const float4*>(f0 + (size_t)b * kL + l0);
    const float4 a = f4[0], bb = f4[1];
    rq[0] = a.x * kInvSamp; rq[1] = a.y * kInvSamp;
    rq[2] = a.z * kInvSamp; rq[3] = a.w * kInvSamp;
    rq[4] = bb.x * kInvSamp; rq[5] = bb.y * kInvSamp;
    rq[6] = bb.z * kInvSamp; rq[7] = bb.w * kInvSamp;
#pragma unroll
    for (int j = 0; j < kT; ++j) tsum += rq[j];
  } else {
#pragma unroll
    for (int j = 0; j < kT; ++j) rq[j] = 0.0f;
  }

  // predecessor aggregate (L2/L3-resident after pass A) -- issued EARLY
  const double aggv = (tid < c) ? agg[(size_t)b * kNChunks + tid] : 0.0;

  // streaming noise loads: plain float4 (L3 keeps them hot across replays)
  float nz[kT * kD];
  if (active) {
    const float4* n4 =
        reinterpret_cast<const float4*>(noise + ((size_t)b * kL + l0) * kD);
#pragma unroll
    for (int i = 0; i < 18; ++i) {
      const float4 x = n4[i];
      nz[4 * i + 0] = x.x; nz[4 * i + 1] = x.y;
      nz[4 * i + 2] = x.z; nz[4 * i + 3] = x.w;
    }
  }

  // ---- predecessor-aggregate reduce (overlaps noise loads)
  red[tid] = aggv;
  __syncthreads();
  for (int ofs = kThreads / 2; ofs > 0; ofs >>= 1) {
    if (tid < ofs) red[tid] += red[tid + ofs];
    __syncthreads();
  }
  const double base = red[0];

  // ---- block-wide inclusive scan (double) of per-thread sums
  sc[tid] = (double)tsum;
  __syncthreads();
  for (int ofs = 1; ofs < kThreads; ofs <<= 1) {
    const double u = (tid >= ofs) ? sc[tid - ofs] : 0.0;
    __syncthreads();
    sc[tid] += u;
    __syncthreads();
  }

  if (!active) return;

  // exclusive phase base (cycles) for this thread's first sample
  const double cbase = base + sc[tid] - (double)tsum;

  float basef[kD], wv[kD];
#pragma unroll
  for (int d = 0; d < kD; ++d) {
    const double ph = (double)(d + 1) * cbase + (double)rand_ini[b * kD + d];
    basef[d] = (float)(ph - floor(ph));
    wv[d] = w[d];
  }

  float ob[kT];
  float pref = 0.0f;
#pragma unroll
  for (int j = 0; j < kT; ++j) {
    pref += rq[j];  // inclusive local prefix
    const float f = rq[j];
    const float au = (f > 0.0f) ? kSineAmp : 0.0f;
    const float namp = (f > 0.0f) ? kNoiseStd : kNoiseUnv;
    float dots = 0.0f, dotn = 0.0f;
#pragma unroll
    for (int d = 0; d < kD; ++d) {
      const float pf = __builtin_amdgcn_fractf(basef[d] + (float)(d + 1) * pref);
      const float sv = __builtin_amdgcn_sinf(pf);  // sin(2*pi*frac)
      dots = fmaf(wv[d], sv, dots);
      dotn = fmaf(wv[d], nz[j * kD + d], dotn);
    }
    const float x = au * dots + namp * dotn;
    const float e = __expf(2.0f * x);
    ob[j] = 1.0f - 2.0f * __builtin_amdgcn_rcpf(e + 1.0f);  // tanh(x)
  }

  float4* o4 = reinterpret_cast<float4*>(out + (size_t)b * kL + l0);
  o4[0] = make_float4(ob[0], ob[1], ob[2], ob[3]);
  o4[1] = make_float4(ob[4], ob[5], ob[6], ob[7]);
}

extern "C" void kernel_launch(void* const* d_in, const int* in_sizes, int n_in,
                              void* d_out, int out_size, void* d_ws,
                              size_t ws_size, hipStream_t stream) {
  const float* f0 = (const float*)d_in[0];
  const float* rand_ini = (const float*)d_in[1];
  const float* noise = (const float*)d_in[2];
  const float* w = (const float*)d_in[3];
  float* out = (float*)d_out;
  double* agg = (double*)d_ws;  // kB * kNChunks doubles = 15104 B

  const dim3 grid(kNChunks, kB), block(kThreads);
  sine_pass_a<<<grid, block, 0, stream>>>(f0, agg);
  sine_emit<<<grid, block, 0, stream>>>(f0, rand_ini, noise, w, agg, out);
}

// Round 10
// 35.116 us; speedup vs baseline: 2.6371x; 1.0154x over previous
//
#include <hip/hip_runtime.h>
#include <math.h>

namespace {
constexpr int kB = 16;
constexpr int kL = 240000;
constexpr int kD = 9;
constexpr float kInvSamp = 1.0f / 24000.0f;
constexpr int kChunk = 2048;
constexpr int kT = 8;              // samples per thread
constexpr int kThreads = 256;      // kChunk / kT
constexpr int kNChunks = 118;      // ceil(240000/2048); last chunk 384 samp
constexpr float kSineAmp = 0.1f;
constexpr float kNoiseStd = 0.003f;
constexpr float kNoiseUnv = (float)(0.1 / 3.0);
}  // namespace

// ---------------- Pass A: per-chunk sum of rq = f0/SR -> agg[b*118+c]
__global__ __launch_bounds__(kThreads) void sine_pass_a(
    const float* __restrict__ f0, double* __restrict__ agg) {
  const int c = blockIdx.x, b = blockIdx.y, tid = threadIdx.x;
  const int l0 = c * kChunk + tid * kT;
  float s = 0.0f;
  if (l0 < kL) {
    const float4* f4 = reinterpret_cast<const float4*>(f0 + (size_t)b * kL + l0);
    const float4 a = f4[0], bb = f4[1];
    s = ((a.x + a.y) + (a.z + a.w)) + ((bb.x + bb.y) + (bb.z + bb.w));
  }
  double v = (double)s * (double)kInvSamp;
#pragma unroll
  for (int ofs = 1; ofs < 64; ofs <<= 1) v += __shfl_xor(v, ofs, 64);
  __shared__ double wt[4];
  const int wid = tid >> 6;
  if ((tid & 63) == 0) wt[wid] = v;
  __syncthreads();
  if (tid == 0) agg[(size_t)b * kNChunks + c] = wt[0] + wt[1] + wt[2] + wt[3];
}

// ---------------- Emit: shuffle-based pred-reduce + scan (1 barrier) + emit
__global__ __launch_bounds__(kThreads) void sine_emit(
    const float* __restrict__ f0, const float* __restrict__ rand_ini,
    const float* __restrict__ noise, const float* __restrict__ w,
    const double* __restrict__ agg, float* __restrict__ out) {
  const int c = blockIdx.x, b = blockIdx.y, tid = threadIdx.x;
  const int lane = tid & 63, wid = tid >> 6;
  const int l0 = c * kChunk + tid * kT;
  const bool active = l0 < kL;

  // ---- f0 -> rq
  float rq[kT];
  float tsum = 0.0f;
  if (active) {
    const float4* f4 = reinterpret_cast<const float4*>(f0 + (size_t)b * kL + l0);
    const float4 a = f4[0], bb = f4[1];
    rq[0] = a.x * kInvSamp; rq[1] = a.y * kInvSamp;
    rq[2] = a.z * kInvSamp; rq[3] = a.w * kInvSamp;
    rq[4] = bb.x * kInvSamp; rq[5] = bb.y * kInvSamp;
    rq[6] = bb.z * kInvSamp; rq[7] = bb.w * kInvSamp;
#pragma unroll
    for (int j = 0; j < kT; ++j) tsum += rq[j];
  } else {
#pragma unroll
    for (int j = 0; j < kT; ++j) rq[j] = 0.0f;
  }

  // predecessor aggregate for this lane (L2-resident after pass A)
  double pv = (tid < c) ? agg[(size_t)b * kNChunks + tid] : 0.0;

  // noise loads: plain float4 (L3-friendly), issued before the scan work
  float nz[kT * kD];
  if (active) {
    const float4* n4 =
        reinterpret_cast<const float4*>(noise + ((size_t)b * kL + l0) * kD);
#pragma unroll
    for (int i = 0; i < 18; ++i) {
      const float4 x = n4[i];
      nz[4 * i + 0] = x.x; nz[4 * i + 1] = x.y;
      nz[4 * i + 2] = x.z; nz[4 * i + 3] = x.w;
    }
  }

  // ---- wave-level reduce (pred aggs) + wave-level scan (tsum), 1 barrier
#pragma unroll
  for (int ofs = 1; ofs < 64; ofs <<= 1) pv += __shfl_xor(pv, ofs, 64);

  double incl = (double)tsum;  // wave-inclusive scan
#pragma unroll
  for (int ofs = 1; ofs < 64; ofs <<= 1) {
    const double u = __shfl_up(incl, ofs, 64);
    if (lane >= ofs) incl += u;
  }

  __shared__ double rtot[4], wtot[4];
  if (lane == 0) rtot[wid] = pv;
  if (lane == 63) wtot[wid] = incl;
  __syncthreads();

  if (!active) return;

  double base = rtot[0] + rtot[1] + rtot[2] + rtot[3];  // pred-chunk sum
#pragma unroll
  for (int k = 0; k < 4; ++k)
    if (k < wid) base += wtot[k];  // preceding-wave totals
  const double cbase = base + incl - (double)tsum;  // exclusive prefix

  float basef[kD], wv[kD];
#pragma unroll
  for (int d = 0; d < kD; ++d) {
    const double ph = (double)(d + 1) * cbase + (double)rand_ini[b * kD + d];
    basef[d] = (float)(ph - floor(ph));
    wv[d] = w[d];
  }

  float ob[kT];
  float pref = 0.0f;
#pragma unroll
  for (int j = 0; j < kT; ++j) {
    pref += rq[j];  // inclusive local prefix
    const float f = rq[j];
    const float au = (f > 0.0f) ? kSineAmp : 0.0f;
    const float namp = (f > 0.0f) ? kNoiseStd : kNoiseUnv;
    float dots = 0.0f, dotn = 0.0f;
#pragma unroll
    for (int d = 0; d < kD; ++d) {
      const float pf = __builtin_amdgcn_fractf(basef[d] + (float)(d + 1) * pref);
      const float sv = __builtin_amdgcn_sinf(pf);  // sin(2*pi*frac)
      dots = fmaf(wv[d], sv, dots);
      dotn = fmaf(wv[d], nz[j * kD + d], dotn);
    }
    const float x = au * dots + namp * dotn;
    const float e = __expf(2.0f * x);
    ob[j] = 1.0f - 2.0f * __builtin_amdgcn_rcpf(e + 1.0f);  // tanh(x)
  }

  float4* o4 = reinterpret_cast<float4*>(out + (size_t)b * kL + l0);
  o4[0] = make_float4(ob[0], ob[1], ob[2], ob[3]);
  o4[1] = make_float4(ob[4], ob[5], ob[6], ob[7]);
}

extern "C" void kernel_launch(void* const* d_in, const int* in_sizes, int n_in,
                              void* d_out, int out_size, void* d_ws,
                              size_t ws_size, hipStream_t stream) {
  const float* f0 = (const float*)d_in[0];
  const float* rand_ini = (const float*)d_in[1];
  const float* noise = (const float*)d_in[2];
  const float* w = (const float*)d_in[3];
  float* out = (float*)d_out;
  double* agg = (double*)d_ws;  // kB * kNChunks doubles = 15104 B

  const dim3 grid(kNChunks, kB), block(kThreads);
  sine_pass_a<<<grid, block, 0, stream>>>(f0, agg);
  sine_emit<<<grid, block, 0, stream>>>(f0, rand_ini, noise, w, agg, out);
}